// Round 3
// baseline (225.148 us; speedup 1.0000x reference)
//
#include <hip/hip_runtime.h>

#define HH   56
#define WW   56
#define HWP  (HH * WW)     // 3136
#define CC   256
#define GG   16
#define CGR  16            // channels per group
#define KT   7
#define KK   49
#define KKG  784
#define RC   64
#define TH   2             // rows per involution block

// ---------------- tiled GEMM: Y[b][m][p] = sum_k W[m][k] * X[b][k][p] + bias[m] ----
template<int MT, int NT, int TM, int TN, int KC, int PAD>
__global__ __launch_bounds__(256)
void gemm_wx(const float* __restrict__ Wm, const float* __restrict__ bias,
             const float* __restrict__ X, float* __restrict__ Y,
             int M, int Kd)
{
    const int b  = blockIdx.z;
    const int bm = blockIdx.y * MT;
    const int bn = blockIdx.x * NT;
    const float* Xb = X + b * Kd * HWP;
    float*       Yb = Y + b * M  * HWP;

    __shared__ __align__(16) float sW[KC][MT + PAD];  // transposed W tile
    __shared__ __align__(16) float sX[KC][NT];

    const int t  = threadIdx.x;
    const int tn = t % (NT / TN);
    const int tm = t / (NT / TN);

    float acc[TM][TN];
#pragma unroll
    for (int i = 0; i < TM; ++i)
#pragma unroll
        for (int j = 0; j < TN; ++j) acc[i][j] = 0.f;

    for (int kc = 0; kc < Kd; kc += KC) {
        for (int i = t; i < MT * KC; i += 256) {
            const int c = i % KC, m = i / KC;
            const int mg = bm + m;
            float v = 0.f;
            if (mg < M) v = Wm[mg * Kd + kc + c];
            sW[c][m] = v;
        }
        for (int i = t; i < KC * NT; i += 256) {
            const int n = i % NT, c = i / NT;
            sX[c][n] = Xb[(kc + c) * HWP + bn + n];
        }
        __syncthreads();
#pragma unroll
        for (int c = 0; c < KC; ++c) {
            float wv[TM], xv[TN];
#pragma unroll
            for (int i = 0; i < TM; i += 4)
                *(float4*)&wv[i] = *(const float4*)&sW[c][tm * TM + i];
            if constexpr (TN >= 4) {
#pragma unroll
                for (int j = 0; j < TN; j += 4)
                    *(float4*)&xv[j] = *(const float4*)&sX[c][tn * TN + j];
            } else {
                *(float2*)&xv[0] = *(const float2*)&sX[c][tn * TN];
            }
#pragma unroll
            for (int i = 0; i < TM; ++i)
#pragma unroll
                for (int j = 0; j < TN; ++j)
                    acc[i][j] += wv[i] * xv[j];
        }
        __syncthreads();
    }
#pragma unroll
    for (int i = 0; i < TM; ++i) {
        const int m = bm + tm * TM + i;
        if (m < M) {
            const float bv = bias[m];
            if constexpr (TN >= 4) {
                float4 v;
                v.x = acc[i][0] + bv; v.y = acc[i][1] + bv;
                v.z = acc[i][2] + bv; v.w = acc[i][3] + bv;
                *(float4*)&Yb[m * HWP + bn + tn * TN] = v;
            } else {
                float2 v;
                v.x = acc[i][0] + bv; v.y = acc[i][1] + bv;
                *(float2*)&Yb[m * HWP + bn + tn * TN] = v;
            }
        }
    }
}

// ---------------- fused kern-gen + involution -------------------------------
__global__ __launch_bounds__(256)
void invol_fused(const float* __restrict__ x, const float* __restrict__ h,
                 const float* __restrict__ sw, const float* __restrict__ sb,
                 float* __restrict__ out)
{
    const int h0 = blockIdx.x * TH;
    const int g  = blockIdx.y;
    const int b  = blockIdx.z;

    __shared__ __align__(16) float sK[KK][TH][WW];        // 21.9 KB
    __shared__ __align__(16) float sX[TH + 6][63][16];    // 32.25 KB (54.2 KB -> 2 blocks/CU)

    const int t = threadIdx.x;

    // zero-fill sX with b128 stores (2016 float4s)
    {
        float4* p = (float4*)&sX[0][0][0];
        const float4 z = make_float4(0.f, 0.f, 0.f, 0.f);
#pragma unroll
        for (int i = 0; i < 8; ++i) {
            const int idx = t + 256 * i;
            if (idx < 2016) p[idx] = z;
        }
    }
    __syncthreads();

    // ---- kern-gen accumulation (register-only; wave-uniform c-half) ----
    const int wave = t >> 6;
    const int half = __builtin_amdgcn_readfirstlane(wave >> 1);   // 0/1, wave-uniform
    const int px   = (t & 63) + 64 * (wave & 1);                  // 0..127, 112 active
    const bool act = px < TH * WW;
    float acc[KK];
    {
        const float* hb = h + ((size_t)b * RC + half * 32) * HWP + h0 * WW + (act ? px : 0);
        float hreg[32];
#pragma unroll
        for (int c = 0; c < 32; ++c) hreg[c] = hb[c * HWP];       // coalesced, L2-hot
        const float* swg = sw + (size_t)g * KK * RC + half * 32;  // wave-uniform
#pragma unroll
        for (int tg = 0; tg < 7; ++tg) {
            float a[7];
#pragma unroll
            for (int j = 0; j < 7; ++j) a[j] = 0.f;
#pragma unroll
            for (int c = 0; c < 32; ++c) {
                const float hv = hreg[c];
#pragma unroll
                for (int j = 0; j < 7; ++j)
                    a[j] += swg[(tg * 7 + j) * RC + c] * hv;      // sgpr * vgpr fmac
            }
#pragma unroll
            for (int j = 0; j < 7; ++j) acc[tg * 7 + j] = a[j];
        }
    }

    // ---- stage x interior, transposed to [row][w+3][ch], float4 row loads ----
    {
        const int ch = t & 15;
        const int wq = t >> 4;            // 0..15, 14 active
        if (wq < 14) {
            const float* xb = x + (size_t)(b * CC + g * CGR + ch) * HWP;
            const int w = wq * 4;
#pragma unroll
            for (int rr = 0; rr < TH + 6; ++rr) {
                const int hh = h0 - 3 + rr;
                if (hh < 0 || hh >= HH) continue;
                const float4 v = *(const float4*)&xb[hh * WW + w];
                sX[rr][w + 3][ch] = v.x;
                sX[rr][w + 4][ch] = v.y;
                sX[rr][w + 5][ch] = v.z;
                sX[rr][w + 6][ch] = v.w;
            }
        }
    }
    __syncthreads();

    // ---- combine halves into sK ----
    if (act && half == 0) {
        const float* sbg = sb + g * KK;                           // wave-uniform
        float* p = &sK[0][0][0];
#pragma unroll
        for (int tap = 0; tap < KK; ++tap)
            p[tap * (TH * WW) + px] = sbg[tap] + acc[tap];
    }
    __syncthreads();
    if (act && half == 1) {
        float* p = &sK[0][0][0];
#pragma unroll
        for (int tap = 0; tap < KK; ++tap)
            p[tap * (TH * WW) + px] += acc[tap];
    }
    __syncthreads();

    // ---- involution ----
    if (t < 224) {                 // 4 chq * 2 r * 28 wg
        const int chg = t & 3;
        const int r   = (t >> 2) & 1;
        const int wg  = t >> 3;
        const int w0  = wg * 2;
        float a00=0,a01=0,a02=0,a03=0, a10=0,a11=0,a12=0,a13=0;
#pragma unroll
        for (int kh = 0; kh < KT; ++kh) {
            const int rr = r + kh;
            float4 xv[8];
#pragma unroll
            for (int j = 0; j < 8; ++j)
                xv[j] = *(const float4*)&sX[rr][w0 + j][chg * 4];
            float2 kv[7];
#pragma unroll
            for (int kw = 0; kw < KT; ++kw)
                kv[kw] = *(const float2*)&sK[kh * KT + kw][r][w0];
#pragma unroll
            for (int kw = 0; kw < KT; ++kw) {
                const float k0 = kv[kw].x, k1 = kv[kw].y;
                const float4 xa = xv[kw], xc = xv[kw + 1];
                a00 += k0 * xa.x; a01 += k0 * xa.y; a02 += k0 * xa.z; a03 += k0 * xa.w;
                a10 += k1 * xc.x; a11 += k1 * xc.y; a12 += k1 * xc.z; a13 += k1 * xc.w;
            }
        }
        const int cbase = b * CC + g * CGR + chg * 4;
        const int poff  = (h0 + r) * WW + w0;
        *(float2*)&out[(cbase + 0) * HWP + poff] = make_float2(a00, a10);
        *(float2*)&out[(cbase + 1) * HWP + poff] = make_float2(a01, a11);
        *(float2*)&out[(cbase + 2) * HWP + poff] = make_float2(a02, a12);
        *(float2*)&out[(cbase + 3) * HWP + poff] = make_float2(a03, a13);
    }
}

extern "C" void kernel_launch(void* const* d_in, const int* in_sizes, int n_in,
                              void* d_out, int out_size, void* d_ws, size_t ws_size,
                              hipStream_t stream)
{
    const float* x  = (const float*)d_in[0];   // (4,256,56,56)
    const float* rw = (const float*)d_in[1];   // (64,256)
    const float* rb = (const float*)d_in[2];   // (64,)
    const float* sw = (const float*)d_in[3];   // (784,64)
    const float* sb = (const float*)d_in[4];   // (784,)
    float* out  = (float*)d_out;               // (4,256,56,56)

    float* hbuf = (float*)d_ws;                // (4,64,3136) = 3.2 MB

    // h = reduce_w @ x + reduce_b
    gemm_wx<64, 32, 4, 2, 32, 4><<<dim3(HWP / 32, 1, 4), 256, 0, stream>>>(
        rw, rb, x, hbuf, RC, CC);
    // fused kern-gen + involution (kern never touches HBM)
    invol_fused<<<dim3(HH / TH, GG, 4), 256, 0, stream>>>(x, hbuf, sw, sb, out);
}

// Round 4
// 179.837 us; speedup vs baseline: 1.2520x; 1.2520x over previous
//
#include <hip/hip_runtime.h>

#define HH   56
#define WW   56
#define HWP  (HH * WW)     // 3136
#define CC   256
#define GG   16
#define CGR  16            // channels per group
#define KT   7
#define KK   49
#define KKG  784
#define RC   64
#define TH   2             // rows per involution block

// ---------------- tiled GEMM: Y[b][m][p] = sum_k W[m][k] * X[b][k][p] + bias[m] ----
template<int MT, int NT, int TM, int TN, int KC, int PAD>
__global__ __launch_bounds__(256)
void gemm_wx(const float* __restrict__ Wm, const float* __restrict__ bias,
             const float* __restrict__ X, float* __restrict__ Y,
             int M, int Kd)
{
    const int b  = blockIdx.z;
    const int bm = blockIdx.y * MT;
    const int bn = blockIdx.x * NT;
    const float* Xb = X + b * Kd * HWP;
    float*       Yb = Y + b * M  * HWP;

    __shared__ __align__(16) float sW[KC][MT + PAD];  // transposed W tile
    __shared__ __align__(16) float sX[KC][NT];

    const int t  = threadIdx.x;
    const int tn = t % (NT / TN);
    const int tm = t / (NT / TN);

    float acc[TM][TN];
#pragma unroll
    for (int i = 0; i < TM; ++i)
#pragma unroll
        for (int j = 0; j < TN; ++j) acc[i][j] = 0.f;

    for (int kc = 0; kc < Kd; kc += KC) {
        for (int i = t; i < MT * KC; i += 256) {
            const int c = i % KC, m = i / KC;
            const int mg = bm + m;
            float v = 0.f;
            if (mg < M) v = Wm[mg * Kd + kc + c];
            sW[c][m] = v;
        }
        for (int i = t; i < KC * NT; i += 256) {
            const int n = i % NT, c = i / NT;
            sX[c][n] = Xb[(kc + c) * HWP + bn + n];
        }
        __syncthreads();
#pragma unroll
        for (int c = 0; c < KC; ++c) {
            float wv[TM], xv[TN];
#pragma unroll
            for (int i = 0; i < TM; i += 4)
                *(float4*)&wv[i] = *(const float4*)&sW[c][tm * TM + i];
            if constexpr (TN >= 4) {
#pragma unroll
                for (int j = 0; j < TN; j += 4)
                    *(float4*)&xv[j] = *(const float4*)&sX[c][tn * TN + j];
            } else {
                *(float2*)&xv[0] = *(const float2*)&sX[c][tn * TN];
            }
#pragma unroll
            for (int i = 0; i < TM; ++i)
#pragma unroll
                for (int j = 0; j < TN; ++j)
                    acc[i][j] += wv[i] * xv[j];
        }
        __syncthreads();
    }
#pragma unroll
    for (int i = 0; i < TM; ++i) {
        const int m = bm + tm * TM + i;
        if (m < M) {
            const float bv = bias[m];
            if constexpr (TN >= 4) {
                float4 v;
                v.x = acc[i][0] + bv; v.y = acc[i][1] + bv;
                v.z = acc[i][2] + bv; v.w = acc[i][3] + bv;
                *(float4*)&Yb[m * HWP + bn + tn * TN] = v;
            } else {
                float2 v;
                v.x = acc[i][0] + bv; v.y = acc[i][1] + bv;
                *(float2*)&Yb[m * HWP + bn + tn * TN] = v;
            }
        }
    }
}

// ---------------- fused kern-gen + involution -------------------------------
// __launch_bounds__(256, 2): LDS (54.2 KB) caps residency at 2 blocks/CU =
// 2 waves/SIMD, so a 256-VGPR budget is occupancy-free. This keeps hreg[64]
// in real VGPRs instead of AGPR spills (rounds 2-3: VGPR capped at 68-72,
// every fmac paid v_accvgpr_read traffic).
__global__ __launch_bounds__(256, 2)
void invol_fused(const float* __restrict__ x, const float* __restrict__ h,
                 const float* __restrict__ sw, const float* __restrict__ sb,
                 float* __restrict__ out)
{
    const int h0 = blockIdx.x * TH;
    const int g  = blockIdx.y;
    const int b  = blockIdx.z;

    __shared__ __align__(16) float sK[KK][TH][WW];        // 21.9 KB
    __shared__ __align__(16) float sX[TH + 6][63][16];    // 32.25 KB (54.2 KB -> 2 blocks/CU)

    const int t = threadIdx.x;

    // zero-fill sX with b128 stores (2016 float4s)
    {
        float4* p = (float4*)&sX[0][0][0];
        const float4 z = make_float4(0.f, 0.f, 0.f, 0.f);
#pragma unroll
        for (int i = 0; i < 8; ++i) {
            const int idx = t + 256 * i;
            if (idx < 2016) p[idx] = z;
        }
    }
    __syncthreads();

    // ---- stage x interior first (global loads issue before the fmac stretch) ----
    {
        const int ch = t & 15;
        const int wq = t >> 4;            // 0..15, 14 active
        if (wq < 14) {
            const float* xb = x + (size_t)(b * CC + g * CGR + ch) * HWP;
            const int w = wq * 4;
#pragma unroll
            for (int rr = 0; rr < TH + 6; ++rr) {
                const int hh = h0 - 3 + rr;
                if (hh < 0 || hh >= HH) continue;
                const float4 v = *(const float4*)&xb[hh * WW + w];
                sX[rr][w + 3][ch] = v.x;
                sX[rr][w + 4][ch] = v.y;
                sX[rr][w + 5][ch] = v.z;
                sX[rr][w + 6][ch] = v.w;
            }
        }
    }

    // ---- kern-gen into sK: taps 0..24 (waves 0-1) / 24..48 (waves 2-3) ----
    {
        const int wave = t >> 6;
        const int half = __builtin_amdgcn_readfirstlane(wave >> 1);  // 0/1, wave-uniform
        const int px   = (t & 63) + 64 * (wave & 1);                 // 0..127, 112 active
        if (px < TH * WW) {
            const float* hb = h + (size_t)b * RC * HWP + h0 * WW + px;
            float hreg[RC];
#pragma unroll
            for (int c = 0; c < RC; ++c) hreg[c] = hb[c * HWP];      // coalesced, L2-hot
            const int tbase = half * 24;                             // 0 or 24 (tap 24 written twice, same value)
            const float* swg = sw + ((size_t)g * KK + tbase) * RC;   // wave-uniform -> s_load
            const float* sbg = sb + g * KK + tbase;
            float* kp = &sK[tbase][0][0] + px;
#pragma unroll
            for (int j = 0; j < 25; ++j) {
                float a0 = 0.f, a1 = 0.f, a2 = 0.f, a3 = 0.f;
#pragma unroll
                for (int c = 0; c < RC; c += 4) {
                    a0 += swg[j * RC + c + 0] * hreg[c + 0];
                    a1 += swg[j * RC + c + 1] * hreg[c + 1];
                    a2 += swg[j * RC + c + 2] * hreg[c + 2];
                    a3 += swg[j * RC + c + 3] * hreg[c + 3];
                }
                kp[j * (TH * WW)] = sbg[j] + ((a0 + a1) + (a2 + a3));
            }
        }
    }
    __syncthreads();

    // ---- involution ----
    if (t < 224) {                 // 4 chq * 2 r * 28 wg
        const int chg = t & 3;
        const int r   = (t >> 2) & 1;
        const int wg  = t >> 3;
        const int w0  = wg * 2;
        float a00=0,a01=0,a02=0,a03=0, a10=0,a11=0,a12=0,a13=0;
#pragma unroll
        for (int kh = 0; kh < KT; ++kh) {
            const int rr = r + kh;
            float4 xv[8];
#pragma unroll
            for (int j = 0; j < 8; ++j)
                xv[j] = *(const float4*)&sX[rr][w0 + j][chg * 4];
            float2 kv[7];
#pragma unroll
            for (int kw = 0; kw < KT; ++kw)
                kv[kw] = *(const float2*)&sK[kh * KT + kw][r][w0];
#pragma unroll
            for (int kw = 0; kw < KT; ++kw) {
                const float k0 = kv[kw].x, k1 = kv[kw].y;
                const float4 xa = xv[kw], xc = xv[kw + 1];
                a00 += k0 * xa.x; a01 += k0 * xa.y; a02 += k0 * xa.z; a03 += k0 * xa.w;
                a10 += k1 * xc.x; a11 += k1 * xc.y; a12 += k1 * xc.z; a13 += k1 * xc.w;
            }
        }
        const int cbase = b * CC + g * CGR + chg * 4;
        const int poff  = (h0 + r) * WW + w0;
        *(float2*)&out[(cbase + 0) * HWP + poff] = make_float2(a00, a10);
        *(float2*)&out[(cbase + 1) * HWP + poff] = make_float2(a01, a11);
        *(float2*)&out[(cbase + 2) * HWP + poff] = make_float2(a02, a12);
        *(float2*)&out[(cbase + 3) * HWP + poff] = make_float2(a03, a13);
    }
}

extern "C" void kernel_launch(void* const* d_in, const int* in_sizes, int n_in,
                              void* d_out, int out_size, void* d_ws, size_t ws_size,
                              hipStream_t stream)
{
    const float* x  = (const float*)d_in[0];   // (4,256,56,56)
    const float* rw = (const float*)d_in[1];   // (64,256)
    const float* rb = (const float*)d_in[2];   // (64,)
    const float* sw = (const float*)d_in[3];   // (784,64)
    const float* sb = (const float*)d_in[4];   // (784,)
    float* out  = (float*)d_out;               // (4,256,56,56)

    float* hbuf = (float*)d_ws;                // (4,64,3136) = 3.2 MB

    // h = reduce_w @ x + reduce_b
    gemm_wx<64, 32, 4, 2, 32, 4><<<dim3(HWP / 32, 1, 4), 256, 0, stream>>>(
        rw, rb, x, hbuf, RC, CC);
    // fused kern-gen + involution (kern never touches HBM)
    invol_fused<<<dim3(HH / TH, GG, 4), 256, 0, stream>>>(x, hbuf, sw, sb, out);
}

// Round 5
// 138.026 us; speedup vs baseline: 1.6312x; 1.3029x over previous
//
#include <hip/hip_runtime.h>
#include <stdint.h>

#define HH   56
#define WW   56
#define HWP  (HH * WW)     // 3136
#define CC   256
#define GG   16
#define CGR  16
#define KT   7
#define KK   49
#define KKG  784
#define RC   64
#define RCP  32            // packed f16 channel-pairs
#define TH   2

typedef _Float16 h2_t __attribute__((ext_vector_type(2)));
union pk32 { uint32_t u; h2_t h; };

static __device__ __forceinline__ h2_t as_h2(uint32_t v) { pk32 p; p.u = v; return p.h; }

// ---- gemm1 (y==0): h2[p][px] = pack_f16(rw[2p]@x + rb, rw[2p+1]@x + rb)
// ---- pack  (y==1, z==0): sw2[i] = pack_f16(sw[2i], sw[2i+1])
__global__ __launch_bounds__(256)
void gemm1_pack(const float* __restrict__ rw, const float* __restrict__ rb,
                const float* __restrict__ x,  const float* __restrict__ sw,
                uint32_t* __restrict__ h2, uint32_t* __restrict__ sw2)
{
    const int t = threadIdx.x;
    if (blockIdx.y == 1) {                       // span_w pre-pack: 25088 u32
        if (blockIdx.z == 0) {
            const int id = blockIdx.x * 256 + t; // grid.x = 98 -> exact
            pk32 p;
            p.h = h2_t{(_Float16)sw[2 * id], (_Float16)sw[2 * id + 1]};
            sw2[id] = p.u;
        }
        return;
    }
    const int b  = blockIdx.z;
    const int bn = blockIdx.x * 32;
    const float* Xb = x + (size_t)b * CC * HWP;

    __shared__ __align__(16) float sW[32][68];   // [c][m], pad 64->68
    __shared__ __align__(16) float sX[32][32];

    const int tn = t % 16;                       // 16 n-cols of 2
    const int tm = t / 16;                       // 16 m-rows of 4
    float acc[4][2];
#pragma unroll
    for (int i = 0; i < 4; ++i) { acc[i][0] = 0.f; acc[i][1] = 0.f; }

    for (int kc = 0; kc < CC; kc += 32) {
        for (int i = t; i < 64 * 32; i += 256) {
            const int c = i % 32, m = i / 32;
            sW[c][m] = rw[m * CC + kc + c];
        }
        {
            const int n = t % 32, c = t / 32;    // 8 c per pass
#pragma unroll
            for (int cc = 0; cc < 32; cc += 8)
                sX[c + cc][n] = Xb[(kc + c + cc) * HWP + bn + n];
        }
        __syncthreads();
#pragma unroll
        for (int c = 0; c < 32; ++c) {
            float wv[4], xv[2];
            *(float4*)&wv[0] = *(const float4*)&sW[c][tm * 4];
            *(float2*)&xv[0] = *(const float2*)&sX[c][tn * 2];
#pragma unroll
            for (int i = 0; i < 4; ++i) {
                acc[i][0] += wv[i] * xv[0];
                acc[i][1] += wv[i] * xv[1];
            }
        }
        __syncthreads();
    }
    // epilogue: pack channel pairs (2p,2p+1) -> u32 planes
    uint32_t* hb = h2 + (size_t)b * RCP * HWP + bn + tn * 2;
#pragma unroll
    for (int pp = 0; pp < 2; ++pp) {
        const int m0 = tm * 4 + pp * 2;
        const float b0 = rb[m0], b1 = rb[m0 + 1];
        pk32 q0, q1;
        q0.h = h2_t{(_Float16)(acc[pp * 2][0] + b0), (_Float16)(acc[pp * 2 + 1][0] + b1)};
        q1.h = h2_t{(_Float16)(acc[pp * 2][1] + b0), (_Float16)(acc[pp * 2 + 1][1] + b1)};
        uint2 v; v.x = q0.u; v.y = q1.u;
        *(uint2*)&hb[(size_t)(tm * 2 + pp) * HWP] = v;
    }
}

// ---------------- fused kern-gen (f16 dot2) + involution --------------------
// LDS 43.2 KB -> 3 blocks/CU. Kern-gen: 800 v_dot2_f32_f16 per thread,
// span_w wave-uniform f16x2 stream through SGPRs, hreg = 32 packed VGPRs.
__global__ __launch_bounds__(256, 3)
void invol_fused(const float* __restrict__ x, const uint32_t* __restrict__ h2,
                 const uint32_t* __restrict__ sw2, const float* __restrict__ sb,
                 float* __restrict__ out)
{
    const int h0 = blockIdx.x * TH;
    const int g  = blockIdx.y;
    const int b  = blockIdx.z;

    __shared__ __align__(16) float    sX[TH + 6][63][16];   // 32.25 KB
    __shared__ __align__(16) _Float16 sK[KK][TH * WW];      // 10.72 KB

    const int t = threadIdx.x;
    const int wave = t >> 6;
    const int half = __builtin_amdgcn_readfirstlane(wave >> 1);  // 0/1
    const int px   = (t & 63) + 64 * (wave & 1);                 // 0..127
    const bool act = px < TH * WW;

    // ---- issue h2 loads first (longest latency) ----
    uint32_t hreg[RCP];
    {
        const uint32_t* hb = h2 + (size_t)b * RCP * HWP + h0 * WW + (act ? px : 0);
#pragma unroll
        for (int c = 0; c < RCP; ++c) hreg[c] = hb[c * HWP];
    }

    // ---- zero halo only (disjoint from interior staging -> no barrier) ----
    {
        // halo cols {0,1,2,59,60,61,62} x 8 rows: 224 float4 (t<224, 1 each)
        if (t < 224) {
            const int col7 = t % 7;
            const int row  = t / 7 % 8;
            const int col  = col7 < 3 ? col7 : col7 + 56;
            *(float4*)&sX[row][col][(t / 56) * 4 % 16] = make_float4(0, 0, 0, 0);
        }
        // rows with invalid hh: zero interior cols 3..58 (224 float4 per row)
#pragma unroll
        for (int rr = 0; rr < TH + 6; ++rr) {
            const int hh = h0 - 3 + rr;
            if (hh >= 0 && hh < HH) continue;
            if (t < 224) {
                const int col = 3 + t / 4;      // 3..58
                *(float4*)&sX[rr][col][(t & 3) * 4] = make_float4(0, 0, 0, 0);
            }
        }
    }

    // ---- stage x interior (valid rows, cols 3..58) ----
    {
        const int ch = t & 15;
        const int wq = t >> 4;                  // 0..15, 14 active
        if (wq < 14) {
            const float* xb = x + (size_t)(b * CC + g * CGR + ch) * HWP;
            const int w = wq * 4;
#pragma unroll
            for (int rr = 0; rr < TH + 6; ++rr) {
                const int hh = h0 - 3 + rr;
                if (hh < 0 || hh >= HH) continue;
                const float4 v = *(const float4*)&xb[hh * WW + w];
                sX[rr][w + 3][ch] = v.x;
                sX[rr][w + 4][ch] = v.y;
                sX[rr][w + 5][ch] = v.z;
                sX[rr][w + 6][ch] = v.w;
            }
        }
    }

    // ---- kern-gen: taps [0,25) / [24,49), f16 dot2 ----
    {
        const int tbase = half * 24;            // tap 24 written twice, same value
        const uint32_t* swg = sw2 + ((size_t)g * KK + tbase) * RCP;  // wave-uniform
        const float*    sbg = sb + g * KK + tbase;
        if (act) {
            _Float16* kp = &sK[tbase][px];
#pragma unroll
            for (int j = 0; j < 25; ++j) {
                float a0 = 0.f, a1 = 0.f, a2 = 0.f, a3 = 0.f;
#pragma unroll
                for (int c = 0; c < RCP; c += 4) {
                    a0 = __builtin_amdgcn_fdot2(as_h2(swg[j * RCP + c + 0]), as_h2(hreg[c + 0]), a0, false);
                    a1 = __builtin_amdgcn_fdot2(as_h2(swg[j * RCP + c + 1]), as_h2(hreg[c + 1]), a1, false);
                    a2 = __builtin_amdgcn_fdot2(as_h2(swg[j * RCP + c + 2]), as_h2(hreg[c + 2]), a2, false);
                    a3 = __builtin_amdgcn_fdot2(as_h2(swg[j * RCP + c + 3]), as_h2(hreg[c + 3]), a3, false);
                }
                kp[j * (TH * WW)] = (_Float16)(sbg[j] + ((a0 + a1) + (a2 + a3)));
            }
        }
    }
    __syncthreads();

    // ---- involution ----
    if (t < 224) {                 // 4 chq * 2 r * 28 wg
        const int chg = t & 3;
        const int r   = (t >> 2) & 1;
        const int wg  = t >> 3;
        const int w0  = wg * 2;
        float a00=0,a01=0,a02=0,a03=0, a10=0,a11=0,a12=0,a13=0;
#pragma unroll
        for (int kh = 0; kh < KT; ++kh) {
            const int rr = r + kh;
            float4 xv[8];
#pragma unroll
            for (int j = 0; j < 8; ++j)
                xv[j] = *(const float4*)&sX[rr][w0 + j][chg * 4];
            float k0v[7], k1v[7];
#pragma unroll
            for (int kw = 0; kw < KT; ++kw) {
                const uint32_t kp = *(const uint32_t*)&sK[kh * KT + kw][r * WW + w0];
                const h2_t kh2 = as_h2(kp);
                k0v[kw] = (float)kh2.x;
                k1v[kw] = (float)kh2.y;
            }
#pragma unroll
            for (int kw = 0; kw < KT; ++kw) {
                const float k0 = k0v[kw], k1 = k1v[kw];
                const float4 xa = xv[kw], xc = xv[kw + 1];
                a00 += k0 * xa.x; a01 += k0 * xa.y; a02 += k0 * xa.z; a03 += k0 * xa.w;
                a10 += k1 * xc.x; a11 += k1 * xc.y; a12 += k1 * xc.z; a13 += k1 * xc.w;
            }
        }
        const int cbase = b * CC + g * CGR + chg * 4;
        const int poff  = (h0 + r) * WW + w0;
        *(float2*)&out[(cbase + 0) * HWP + poff] = make_float2(a00, a10);
        *(float2*)&out[(cbase + 1) * HWP + poff] = make_float2(a01, a11);
        *(float2*)&out[(cbase + 2) * HWP + poff] = make_float2(a02, a12);
        *(float2*)&out[(cbase + 3) * HWP + poff] = make_float2(a03, a13);
    }
}

extern "C" void kernel_launch(void* const* d_in, const int* in_sizes, int n_in,
                              void* d_out, int out_size, void* d_ws, size_t ws_size,
                              hipStream_t stream)
{
    const float* x  = (const float*)d_in[0];   // (4,256,56,56)
    const float* rw = (const float*)d_in[1];   // (64,256)
    const float* rb = (const float*)d_in[2];   // (64,)
    const float* sw = (const float*)d_in[3];   // (784,64)
    const float* sb = (const float*)d_in[4];   // (784,)
    float* out  = (float*)d_out;               // (4,256,56,56)

    uint32_t* h2  = (uint32_t*)d_ws;           // (4,32,3136) u32 = 1.6 MB
    uint32_t* sw2 = h2 + 4 * RCP * HWP;        // 25088 u32   = 100 KB

    // gemm1 (y==0) + span_w f16 pre-pack (y==1)
    gemm1_pack<<<dim3(HWP / 32, 2, 4), 256, 0, stream>>>(rw, rb, x, sw, h2, sw2);
    // fused f16-dot2 kern-gen + involution
    invol_fused<<<dim3(HH / TH, GG, 4), 256, 0, stream>>>(x, h2, sw2, sb, out);
}

// Round 6
// 116.540 us; speedup vs baseline: 1.9319x; 1.1844x over previous
//
#include <hip/hip_runtime.h>
#include <stdint.h>

#define HH   56
#define WW   56
#define HWP  (HH * WW)     // 3136
#define CC   256
#define GG   16
#define CGR  16
#define KT   7
#define KK   49
#define RC   64
#define RCP  32            // packed f16 channel-pairs
#define TH   2
#define TPAD 113           // LDS_T row pitch (u32): odd -> spreads banks

typedef _Float16 h2_t __attribute__((ext_vector_type(2)));
typedef _Float16 v8h  __attribute__((ext_vector_type(8)));
typedef float    v4f  __attribute__((ext_vector_type(4)));
union pk32 { uint32_t u; h2_t h; };
union frag { uint32_t u[4]; v8h h; };

static __device__ __forceinline__ h2_t as_h2(uint32_t v) { pk32 p; p.u = v; return p.h; }

// ---- gemm1 (y==0): h2[p][px] = pack_f16(rw[2p]@x + rb, rw[2p+1]@x + rb)
// ---- pack  (y==1, z==0): sw2[i] = pack_f16(sw[2i], sw[2i+1])
__global__ __launch_bounds__(256)
void gemm1_pack(const float* __restrict__ rw, const float* __restrict__ rb,
                const float* __restrict__ x,  const float* __restrict__ sw,
                uint32_t* __restrict__ h2, uint32_t* __restrict__ sw2)
{
    const int t = threadIdx.x;
    if (blockIdx.y == 1) {                       // span_w pre-pack: 25088 u32
        if (blockIdx.z == 0) {
            const int id = blockIdx.x * 256 + t; // grid.x = 98 -> exact
            pk32 p;
            p.h = h2_t{(_Float16)sw[2 * id], (_Float16)sw[2 * id + 1]};
            sw2[id] = p.u;
        }
        return;
    }
    const int b  = blockIdx.z;
    const int bn = blockIdx.x * 32;
    const float* Xb = x + (size_t)b * CC * HWP;

    __shared__ __align__(16) float sW[32][68];
    __shared__ __align__(16) float sX[32][32];

    const int tn = t % 16;
    const int tm = t / 16;
    float acc[4][2];
#pragma unroll
    for (int i = 0; i < 4; ++i) { acc[i][0] = 0.f; acc[i][1] = 0.f; }

    for (int kc = 0; kc < CC; kc += 32) {
        for (int i = t; i < 64 * 32; i += 256) {
            const int c = i % 32, m = i / 32;
            sW[c][m] = rw[m * CC + kc + c];
        }
        {
            const int n = t % 32, c = t / 32;
#pragma unroll
            for (int cc = 0; cc < 32; cc += 8)
                sX[c + cc][n] = Xb[(kc + c + cc) * HWP + bn + n];
        }
        __syncthreads();
#pragma unroll
        for (int c = 0; c < 32; ++c) {
            float wv[4], xv[2];
            *(float4*)&wv[0] = *(const float4*)&sW[c][tm * 4];
            *(float2*)&xv[0] = *(const float2*)&sX[c][tn * 2];
#pragma unroll
            for (int i = 0; i < 4; ++i) {
                acc[i][0] += wv[i] * xv[0];
                acc[i][1] += wv[i] * xv[1];
            }
        }
        __syncthreads();
    }
    uint32_t* hb = h2 + (size_t)b * RCP * HWP + bn + tn * 2;
#pragma unroll
    for (int pp = 0; pp < 2; ++pp) {
        const int m0 = tm * 4 + pp * 2;
        const float b0 = rb[m0], b1 = rb[m0 + 1];
        pk32 q0, q1;
        q0.h = h2_t{(_Float16)(acc[pp * 2][0] + b0), (_Float16)(acc[pp * 2 + 1][0] + b1)};
        q1.h = h2_t{(_Float16)(acc[pp * 2][1] + b0), (_Float16)(acc[pp * 2 + 1][1] + b1)};
        uint2 v; v.x = q0.u; v.y = q1.u;
        *(uint2*)&hb[(size_t)(tm * 2 + pp) * HWP] = v;
    }
}

// ---------------- fused MFMA kern-gen + involution --------------------------
// Per block (b,g,2-row strip): K[49][112] = SW[49][64] @ H[64][112] via
// mfma_f32_16x16x32_f16 (wave = m-tile; A-frag from global sw2; B-frag from
// LDS_T transpose buffer). LDS_T overlaid with sK (disjoint live ranges).
__global__ __launch_bounds__(256, 3)
void invol_fused(const float* __restrict__ x, const uint32_t* __restrict__ h2,
                 const uint32_t* __restrict__ sw2, const float* __restrict__ sb,
                 float* __restrict__ out)
{
    const int h0 = blockIdx.x * TH;
    const int g  = blockIdx.y;
    const int b  = blockIdx.z;

    __shared__ __align__(16) float    sX[TH + 6][63][16];     // 32.25 KB
    __shared__ __align__(16) uint32_t U[RCP * TPAD];          // 14.46 KB: LDS_T, then sK
    uint32_t* ldsT = U;                                       // [c2][TPAD]
    _Float16* sK   = (_Float16*)U;                            // [49][112] f16 = 10.7 KB

    const int t    = threadIdx.x;
    const int wave = t >> 6;           // = m-tile
    const int lane = t & 63;
    const int quad = lane >> 4;
    const int n16  = lane & 15;

    // ---- A-frags straight from global (wave-uniform row block, L2-hot) ----
    const int mtap = wave * 16 + n16;              // A row (tap), clamp OOB
    const int tapc = mtap > 48 ? 48 : mtap;
    const uint32_t* swr = sw2 + ((size_t)g * KK + tapc) * RCP + quad * 4;
    frag a0, a1;
    *(uint4*)a0.u = *(const uint4*)swr;            // k-chunk 0 (c 0..31)
    *(uint4*)a1.u = *(const uint4*)(swr + 16);     // k-chunk 1 (c 32..63)

    // ---- bias per C-row (tap = wave*16 + quad*4 + reg) ----
    float bvv[4];
#pragma unroll
    for (int reg = 0; reg < 4; ++reg) {
        const int tp = wave * 16 + quad * 4 + reg;
        bvv[reg] = (tp < KK) ? sb[g * KK + tp] : 0.f;
    }

    // ---- stage H transpose: LDS_T[c2][px], 3584 u32, coalesced px-major ----
    {
        const uint32_t* hb = h2 + (size_t)b * RCP * HWP + h0 * WW;
#pragma unroll
        for (int k = 0; k < 14; ++k) {
            const int i  = t + 256 * k;
            const int c2 = i / 112, px = i % 112;
            ldsT[c2 * TPAD + px] = hb[(size_t)c2 * HWP + px];
        }
    }

    // ---- zero halo of sX (disjoint from interior staging) ----
    if (t < 224) {
        const int col7 = t % 7;
        const int row  = (t / 7) % 8;
        const int col  = col7 < 3 ? col7 : col7 + 56;
        *(float4*)&sX[row][col][(t / 56) * 4] = make_float4(0, 0, 0, 0);
    }
#pragma unroll
    for (int rr = 0; rr < TH + 6; ++rr) {
        const int hh = h0 - 3 + rr;
        if (hh >= 0 && hh < HH) continue;
        if (t < 224) {
            const int col = 3 + t / 4;
            *(float4*)&sX[rr][col][(t & 3) * 4] = make_float4(0, 0, 0, 0);
        }
    }

    // ---- stage x interior (f32, phase-C layout [row][w+3][ch]) ----
    {
        const int ch = t & 15;
        const int wq = t >> 4;
        if (wq < 14) {
            const float* xb = x + (size_t)(b * CC + g * CGR + ch) * HWP;
            const int w = wq * 4;
#pragma unroll
            for (int rr = 0; rr < TH + 6; ++rr) {
                const int hh = h0 - 3 + rr;
                if (hh < 0 || hh >= HH) continue;
                const float4 v = *(const float4*)&xb[hh * WW + w];
                sX[rr][w + 3][ch] = v.x;
                sX[rr][w + 4][ch] = v.y;
                sX[rr][w + 5][ch] = v.z;
                sX[rr][w + 6][ch] = v.w;
            }
        }
    }
    __syncthreads();                               // barrier 1: LDS_T + sX ready

    // ---- MFMA: wave's m-tile x 7 n-tiles x 2 k-chunks ----
    v4f acc[7];
#pragma unroll
    for (int nt = 0; nt < 7; ++nt) acc[nt] = v4f{0.f, 0.f, 0.f, 0.f};
#pragma unroll
    for (int nt = 0; nt < 7; ++nt) {
        const int px = nt * 16 + n16;
        frag b0, b1;
#pragma unroll
        for (int jj = 0; jj < 4; ++jj) {
            b0.u[jj] = ldsT[(quad * 4 + jj) * TPAD + px];        // k 0..31
            b1.u[jj] = ldsT[(16 + quad * 4 + jj) * TPAD + px];   // k 32..63
        }
        acc[nt] = __builtin_amdgcn_mfma_f32_16x16x32_f16(a0.h, b0.h, acc[nt], 0, 0, 0);
        acc[nt] = __builtin_amdgcn_mfma_f32_16x16x32_f16(a1.h, b1.h, acc[nt], 0, 0, 0);
    }
    __syncthreads();                               // barrier 2: B-reads done, reuse U as sK

    // ---- C-frag (col=n16, row=quad*4+reg) + bias -> sK f16 ----
#pragma unroll
    for (int nt = 0; nt < 7; ++nt) {
        const int px = nt * 16 + n16;
#pragma unroll
        for (int reg = 0; reg < 4; ++reg) {
            const int tp = wave * 16 + quad * 4 + reg;
            if (tp < KK)
                sK[tp * (TH * WW) + px] = (_Float16)(acc[nt][reg] + bvv[reg]);
        }
    }
    __syncthreads();                               // barrier 3: sK ready

    // ---- involution (f32 x, f16 kern) ----
    if (t < 224) {                 // 4 chq * 2 r * 28 wg
        const int chg = t & 3;
        const int r   = (t >> 2) & 1;
        const int wg  = t >> 3;
        const int w0  = wg * 2;
        float a00=0,a01=0,a02=0,a03=0, a10=0,a11=0,a12=0,a13=0;
#pragma unroll
        for (int kh = 0; kh < KT; ++kh) {
            const int rr = r + kh;
            float4 xv[8];
#pragma unroll
            for (int j = 0; j < 8; ++j)
                xv[j] = *(const float4*)&sX[rr][w0 + j][chg * 4];
            float k0v[7], k1v[7];
#pragma unroll
            for (int kw = 0; kw < KT; ++kw) {
                const uint32_t kp = *(const uint32_t*)&sK[(kh * KT + kw) * (TH * WW) + r * WW + w0];
                const h2_t kh2 = as_h2(kp);
                k0v[kw] = (float)kh2.x;
                k1v[kw] = (float)kh2.y;
            }
#pragma unroll
            for (int kw = 0; kw < KT; ++kw) {
                const float k0 = k0v[kw], k1 = k1v[kw];
                const float4 xa = xv[kw], xc = xv[kw + 1];
                a00 += k0 * xa.x; a01 += k0 * xa.y; a02 += k0 * xa.z; a03 += k0 * xa.w;
                a10 += k1 * xc.x; a11 += k1 * xc.y; a12 += k1 * xc.z; a13 += k1 * xc.w;
            }
        }
        const int cbase = b * CC + g * CGR + chg * 4;
        const int poff  = (h0 + r) * WW + w0;
        *(float2*)&out[(cbase + 0) * HWP + poff] = make_float2(a00, a10);
        *(float2*)&out[(cbase + 1) * HWP + poff] = make_float2(a01, a11);
        *(float2*)&out[(cbase + 2) * HWP + poff] = make_float2(a02, a12);
        *(float2*)&out[(cbase + 3) * HWP + poff] = make_float2(a03, a13);
    }
}

extern "C" void kernel_launch(void* const* d_in, const int* in_sizes, int n_in,
                              void* d_out, int out_size, void* d_ws, size_t ws_size,
                              hipStream_t stream)
{
    const float* x  = (const float*)d_in[0];   // (4,256,56,56)
    const float* rw = (const float*)d_in[1];   // (64,256)
    const float* rb = (const float*)d_in[2];   // (64,)
    const float* sw = (const float*)d_in[3];   // (784,64)
    const float* sb = (const float*)d_in[4];   // (784,)
    float* out  = (float*)d_out;               // (4,256,56,56)

    uint32_t* h2  = (uint32_t*)d_ws;           // (4,32,3136) u32 = 1.6 MB
    uint32_t* sw2 = h2 + 4 * RCP * HWP;        // 25088 u32   = 100 KB

    gemm1_pack<<<dim3(HWP / 32, 2, 4), 256, 0, stream>>>(rw, rb, x, sw, h2, sw2);
    invol_fused<<<dim3(HH / TH, GG, 4), 256, 0, stream>>>(x, h2, sw2, sb, out);
}

// Round 7
// 109.857 us; speedup vs baseline: 2.0495x; 1.0608x over previous
//
#include <hip/hip_runtime.h>
#include <stdint.h>

#define HH   56
#define WW   56
#define HWP  (HH * WW)     // 3136
#define CC   256
#define GG   16
#define CGR  16
#define KT   7
#define KK   49
#define RCP  32            // packed f16 channel-pairs (64 ch)
#define TH   2
#define XP   548           // sX ch-plane pitch (f32): 8*68+4, %32=4 -> ch bank spread
#define RP   68            // sX row pitch (f32): 4 left halo + 56 + 8 right
#define TP   116           // ldsT pitch (u32): %32=20 -> quad bank spread

typedef _Float16 h2_t __attribute__((ext_vector_type(2)));
typedef _Float16 v8h  __attribute__((ext_vector_type(8)));
typedef float    v4f  __attribute__((ext_vector_type(4)));
union pk32 { uint32_t u; h2_t h; };
union frag { uint32_t u[4]; v8h h; };

// ---- pack f32->f16x2: sw2 (25088 u32) then rw2 (8192 u32); grid 130*256 exact
__global__ __launch_bounds__(256)
void pack_weights(const float* __restrict__ sw, const float* __restrict__ rw,
                  uint32_t* __restrict__ sw2, uint32_t* __restrict__ rw2)
{
    const int id = blockIdx.x * 256 + threadIdx.x;
    if (id < 25088) {
        pk32 p; p.h = h2_t{(_Float16)sw[2 * id], (_Float16)sw[2 * id + 1]};
        sw2[id] = p.u;
    } else {
        const int j = id - 25088;
        pk32 p; p.h = h2_t{(_Float16)rw[2 * j], (_Float16)rw[2 * j + 1]};
        rw2[j] = p.u;
    }
}

// ---- gemm1 via MFMA: h2[b][p][px] = pack_f16 pairs of rw@x + rb
// grid (98,1,4); px-tile 32; K=256 in 4 chunks of 64, double-buffered LDS.
__global__ __launch_bounds__(256)
void gemm1_mfma(const uint32_t* __restrict__ rw2, const float* __restrict__ rb,
                const float* __restrict__ x, uint32_t* __restrict__ h2)
{
    const int b   = blockIdx.z;
    const int px0 = blockIdx.x * 32;
    const int t = threadIdx.x;
    const int wave = t >> 6, lane = t & 63, quad = lane >> 4, n16 = lane & 15;

    __shared__ __align__(16) uint32_t ldsB[2][32][36];   // [buf][c2][px], 9.2 KB

    const int c2l = t >> 3;            // 0..31 (c-pair within chunk)
    const int px4 = t & 7;             // 0..7  (f4 column)
    const float* xb = x + (size_t)b * CC * HWP + px0 + 4 * px4;

    v4f acc[2];
    acc[0] = v4f{0.f,0.f,0.f,0.f}; acc[1] = v4f{0.f,0.f,0.f,0.f};

    // stage chunk 0
    {
        const int c = 2 * c2l;
        const float4 a  = *(const float4*)&xb[(size_t)c * HWP];
        const float4 bb = *(const float4*)&xb[(size_t)(c + 1) * HWP];
        pk32 u0,u1,u2,u3;
        u0.h = h2_t{(_Float16)a.x, (_Float16)bb.x};
        u1.h = h2_t{(_Float16)a.y, (_Float16)bb.y};
        u2.h = h2_t{(_Float16)a.z, (_Float16)bb.z};
        u3.h = h2_t{(_Float16)a.w, (_Float16)bb.w};
        uint4 w; w.x=u0.u; w.y=u1.u; w.z=u2.u; w.w=u3.u;
        *(uint4*)&ldsB[0][c2l][4 * px4] = w;
    }
    __syncthreads();

    const uint32_t* rwm = rw2 + (size_t)(wave * 16 + n16) * 128;   // A row (m)
#pragma unroll
    for (int k = 0; k < 4; ++k) {
        if (k < 3) {                    // prefetch next chunk into other buffer
            const int c = (k + 1) * 64 + 2 * c2l;
            const float4 a  = *(const float4*)&xb[(size_t)c * HWP];
            const float4 bb = *(const float4*)&xb[(size_t)(c + 1) * HWP];
            pk32 u0,u1,u2,u3;
            u0.h = h2_t{(_Float16)a.x, (_Float16)bb.x};
            u1.h = h2_t{(_Float16)a.y, (_Float16)bb.y};
            u2.h = h2_t{(_Float16)a.z, (_Float16)bb.z};
            u3.h = h2_t{(_Float16)a.w, (_Float16)bb.w};
            uint4 w; w.x=u0.u; w.y=u1.u; w.z=u2.u; w.w=u3.u;
            *(uint4*)&ldsB[(k + 1) & 1][c2l][4 * px4] = w;
        }
        frag a0, a1;
        *(uint4*)a0.u = *(const uint4*)&rwm[k * 32 + quad * 4];
        *(uint4*)a1.u = *(const uint4*)&rwm[k * 32 + 16 + quad * 4];
        const uint32_t (*B)[36] = ldsB[k & 1];
#pragma unroll
        for (int nt = 0; nt < 2; ++nt) {
            frag b0, b1;
#pragma unroll
            for (int jj = 0; jj < 4; ++jj) {
                b0.u[jj] = B[quad * 4 + jj][nt * 16 + n16];
                b1.u[jj] = B[16 + quad * 4 + jj][nt * 16 + n16];
            }
            acc[nt] = __builtin_amdgcn_mfma_f32_16x16x32_f16(a0.h, b0.h, acc[nt], 0, 0, 0);
            acc[nt] = __builtin_amdgcn_mfma_f32_16x16x32_f16(a1.h, b1.h, acc[nt], 0, 0, 0);
        }
        __syncthreads();
    }
    // epilogue: C (col=n16=px, row=quad*4+reg=m) -> pack pairs -> h2 planes
    uint32_t* hb = h2 + (size_t)b * RCP * HWP + px0;
#pragma unroll
    for (int nt = 0; nt < 2; ++nt) {
#pragma unroll
        for (int pr = 0; pr < 2; ++pr) {
            const int m0 = wave * 16 + quad * 4 + 2 * pr;
            pk32 q;
            q.h = h2_t{(_Float16)(acc[nt][2 * pr] + rb[m0]),
                       (_Float16)(acc[nt][2 * pr + 1] + rb[m0 + 1])};
            hb[(size_t)(wave * 8 + quad * 2 + pr) * HWP + nt * 16 + n16] = q.u;
        }
    }
}

// ---- fused MFMA kern-gen + involution (px-major sX, f32 sK) ---------------
__global__ __launch_bounds__(256, 2)
void invol_fused(const float* __restrict__ x, const uint32_t* __restrict__ h2,
                 const uint32_t* __restrict__ sw2, const float* __restrict__ sb,
                 float* __restrict__ out)
{
    const int h0 = blockIdx.x * TH;
    const int g  = blockIdx.y;
    const int b  = blockIdx.z;

    __shared__ __align__(16) float    sX[16 * XP];     // 35.07 KB px-major x
    __shared__ __align__(16) uint32_t ldsT[32 * TP];   // 14.85 KB h2 strip
    __shared__ __align__(16) float    sK[KK * 112];    // 21.95 KB kern f32
                                                       // total 71.9 KB -> 2 blocks/CU
    const int t = threadIdx.x;
    const int wave = t >> 6, lane = t & 63, quad = lane >> 4, n16 = lane & 15;

    // A-frags from global sw2 (wave-uniform row block, L2-hot)
    const int mt0 = wave * 16 + n16;
    const int mtap = mt0 > 48 ? 48 : mt0;
    const uint32_t* swr = sw2 + ((size_t)g * KK + mtap) * RCP + quad * 4;
    frag a0, a1;
    *(uint4*)a0.u = *(const uint4*)swr;
    *(uint4*)a1.u = *(const uint4*)(swr + 16);

    float bvv[4];
#pragma unroll
    for (int reg = 0; reg < 4; ++reg) {
        const int tp = wave * 16 + quad * 4 + reg;
        bvv[reg] = (tp < KK) ? sb[g * KK + tp] : 0.f;
    }

    // stage h2 strip -> ldsT (coalesced 112-runs)
    {
        const uint32_t* hb = h2 + (size_t)b * RCP * HWP + h0 * WW;
#pragma unroll
        for (int k = 0; k < 14; ++k) {
            const int i = t + 256 * k;
            const int px = i % 112, c2 = i / 112;
            ldsT[c2 * TP + px] = hb[(size_t)c2 * HWP + px];
        }
    }

    // halo zero: cols 0..3 and 60..63 per (ch,row) — exactly 1 f4 per thread
    {
        const int hc = t & 1, rr = (t >> 1) & 7, ch = t >> 4;
        *(float4*)&sX[ch * XP + rr * RP + (hc ? 60 : 0)] = make_float4(0,0,0,0);
    }

    // interior stage (lane->w, coalesced 224-B runs); invalid rows write zero
    {
        const float* xb = x + (size_t)(b * CC + g * CGR) * HWP;
#pragma unroll
        for (int k = 0; k < 7; ++k) {
            const int i = t + 256 * k;            // 1792 f4 slots exact
            const int w4 = i % 14, rr = (i / 14) % 8, ch = i / 112;
            const int hh = h0 - 3 + rr;
            float4 v = make_float4(0,0,0,0);
            if (hh >= 0 && hh < HH)
                v = *(const float4*)&xb[(size_t)ch * HWP + hh * WW + 4 * w4];
            *(float4*)&sX[ch * XP + rr * RP + 4 + 4 * w4] = v;
        }
    }
    __syncthreads();                               // barrier 1

    // MFMA: K[49][112] = SW[49][64] @ H[64][112]
    v4f acc[7];
#pragma unroll
    for (int nt = 0; nt < 7; ++nt) acc[nt] = v4f{0.f,0.f,0.f,0.f};
#pragma unroll
    for (int nt = 0; nt < 7; ++nt) {
        const int px = nt * 16 + n16;
        frag b0, b1;
#pragma unroll
        for (int jj = 0; jj < 4; ++jj) {
            b0.u[jj] = ldsT[(quad * 4 + jj) * TP + px];
            b1.u[jj] = ldsT[(16 + quad * 4 + jj) * TP + px];
        }
        acc[nt] = __builtin_amdgcn_mfma_f32_16x16x32_f16(a0.h, b0.h, acc[nt], 0, 0, 0);
        acc[nt] = __builtin_amdgcn_mfma_f32_16x16x32_f16(a1.h, b1.h, acc[nt], 0, 0, 0);
    }
    // epilogue -> sK f32 (no truncation, no cvt in phase C)
#pragma unroll
    for (int nt = 0; nt < 7; ++nt) {
        const int px = nt * 16 + n16;
#pragma unroll
        for (int reg = 0; reg < 4; ++reg) {
            const int tp = wave * 16 + quad * 4 + reg;
            if (tp < KK) sK[tp * 112 + px] = acc[nt][reg] + bvv[reg];
        }
    }
    __syncthreads();                               // barrier 2

    // involution: thread = (ch, r, wq); 2 w-blocks of 4 outputs each
    if (t < 224) {
        const int ch = t & 15;
        const int q  = t >> 4;        // 0..13
        const int r  = q & 1;
        const int wq = q >> 1;        // 0..6
        const float* xc = sX + ch * XP;
        float* op = out + (size_t)(b * CC + g * CGR + ch) * HWP + (h0 + r) * WW;
#pragma unroll
        for (int wb = 0; wb < 2; ++wb) {
            const int w0 = 4 * wq + 28 * wb;
            float o0=0.f, o1=0.f, o2=0.f, o3=0.f;
#pragma unroll
            for (int kh = 0; kh < KT; ++kh) {
                const int rr = r + kh;
                const float* xr = xc + rr * RP + w0;   // xr[i] = x at width w0-4+i
                float xf[12];
                *(float4*)&xf[0] = *(const float4*)&xr[0];
                *(float4*)&xf[4] = *(const float4*)&xr[4];
                *(float4*)&xf[8] = *(const float4*)&xr[8];
                const float* kp = sK + (kh * KT) * 112 + r * WW + w0;  // broadcast reads
#pragma unroll
                for (int kw = 0; kw < KT; ++kw) {
                    const float4 kf = *(const float4*)&kp[kw * 112];
                    o0 += kf.x * xf[kw + 1];
                    o1 += kf.y * xf[kw + 2];
                    o2 += kf.z * xf[kw + 3];
                    o3 += kf.w * xf[kw + 4];
                }
            }
            *(float4*)&op[w0] = make_float4(o0, o1, o2, o3);
        }
    }
}

extern "C" void kernel_launch(void* const* d_in, const int* in_sizes, int n_in,
                              void* d_out, int out_size, void* d_ws, size_t ws_size,
                              hipStream_t stream)
{
    const float* x  = (const float*)d_in[0];   // (4,256,56,56)
    const float* rw = (const float*)d_in[1];   // (64,256)
    const float* rb = (const float*)d_in[2];   // (64,)
    const float* sw = (const float*)d_in[3];   // (784,64)
    const float* sb = (const float*)d_in[4];   // (784,)
    float* out  = (float*)d_out;               // (4,256,56,56)

    uint32_t* h2  = (uint32_t*)d_ws;           // (4,32,3136) u32 = 1.6 MB
    uint32_t* sw2 = h2 + 4 * RCP * HWP;        // 25088 u32
    uint32_t* rw2 = sw2 + 25088;               // 8192 u32

    pack_weights<<<dim3(130, 1, 1), 256, 0, stream>>>(sw, rw, sw2, rw2);
    gemm1_mfma<<<dim3(HWP / 32, 1, 4), 256, 0, stream>>>(rw2, rb, x, h2);
    invol_fused<<<dim3(HH / TH, GG, 4), 256, 0, stream>>>(x, h2, sw2, sb, out);
}

// Round 9
// 96.143 us; speedup vs baseline: 2.3418x; 1.1426x over previous
//
#include <hip/hip_runtime.h>
#include <hip/hip_fp16.h>
#include <stdint.h>

#define HH   56
#define WW   56
#define HWP  3136
#define CC   256
#define GG   16
#define CGR  16
#define KT   7
#define KK   49
#define RCP  32            // packed f16 channel-pairs (64 ch)
#define TH   2
#define XROW 32            // u32 per sXh row (64 f16)
#define XPL  260           // u32 per sXh ch-plane (8*32+4; %32=4 -> ch bank spread, 16B-aligned)

typedef _Float16 h2_t  __attribute__((ext_vector_type(2)));
typedef __fp16   fp16x2 __attribute__((ext_vector_type(2)));
typedef _Float16 v8h  __attribute__((ext_vector_type(8)));
typedef float    v4f  __attribute__((ext_vector_type(4)));
union pk32 { uint32_t u; h2_t h; __half2 hh; fp16x2 f; };
union frag { uint32_t u[4]; v8h h; };

static __device__ __forceinline__ uint32_t pkrtz(float a, float b) {
    pk32 p; p.f = __builtin_amdgcn_cvt_pkrtz(a, b); return p.u;
}

// ---- pack f32->f16x2: sw2 (25088 u32) then rw2 (8192 u32); grid 130*256 exact
__global__ __launch_bounds__(256)
void pack_weights(const float* __restrict__ sw, const float* __restrict__ rw,
                  uint32_t* __restrict__ sw2, uint32_t* __restrict__ rw2)
{
    const int id = blockIdx.x * 256 + threadIdx.x;
    if (id < 25088) sw2[id] = pkrtz(sw[2 * id], sw[2 * id + 1]);
    else            rw2[id - 25088] = pkrtz(rw[2 * (id - 25088)], rw[2 * (id - 25088) + 1]);
}

// ---- gemm1 via MFMA: h2[b][p][px] planes; px-tile 32, K=256 prefetched upfront
__global__ __launch_bounds__(256)
void gemm1_mfma(const uint32_t* __restrict__ rw2, const float* __restrict__ rb,
                const float* __restrict__ x, uint32_t* __restrict__ h2)
{
    const int b = blockIdx.z, px0 = blockIdx.x * 32;
    const int t = threadIdx.x;
    const int wave = t >> 6, lane = t & 63, quad = lane >> 4, n16 = lane & 15;

    __shared__ __align__(16) uint32_t ldsB[2][8 * 128];   // [buf][q4*128+px*4+jj], 8 KB

    const int px = t & 31;          // staging: 32 px x 8 q4
    const int q4 = t >> 5;
    const float* xb = x + (size_t)b * CC * HWP + px0 + px;

    // prefetch all 4 K-chunks (no per-chunk global latency later)
    float r[4][8];
#pragma unroll
    for (int k = 0; k < 4; ++k)
#pragma unroll
        for (int cc = 0; cc < 8; ++cc)
            r[k][cc] = xb[(size_t)(k * 64 + q4 * 8 + cc) * HWP];

    {   // stage chunk 0
        uint4 w;
        w.x = pkrtz(r[0][0], r[0][1]); w.y = pkrtz(r[0][2], r[0][3]);
        w.z = pkrtz(r[0][4], r[0][5]); w.w = pkrtz(r[0][6], r[0][7]);
        *(uint4*)&ldsB[0][q4 * 128 + px * 4] = w;
    }
    __syncthreads();

    v4f acc[2];
    acc[0] = v4f{0.f,0.f,0.f,0.f}; acc[1] = v4f{0.f,0.f,0.f,0.f};
    const uint32_t* rwm = rw2 + (size_t)(wave * 16 + n16) * 128;
#pragma unroll
    for (int k = 0; k < 4; ++k) {
        if (k < 3) {    // stage next chunk into other buffer (register source only)
            uint4 w;
            w.x = pkrtz(r[k+1][0], r[k+1][1]); w.y = pkrtz(r[k+1][2], r[k+1][3]);
            w.z = pkrtz(r[k+1][4], r[k+1][5]); w.w = pkrtz(r[k+1][6], r[k+1][7]);
            *(uint4*)&ldsB[(k + 1) & 1][q4 * 128 + px * 4] = w;
        }
        frag a0, a1;
        *(uint4*)a0.u = *(const uint4*)&rwm[k * 32 + quad * 4];
        *(uint4*)a1.u = *(const uint4*)&rwm[k * 32 + 16 + quad * 4];
        const uint32_t* B = ldsB[k & 1];
#pragma unroll
        for (int nt = 0; nt < 2; ++nt) {
            frag b0, b1;
            *(uint4*)b0.u = *(const uint4*)&B[quad * 128 + (nt * 16 + n16) * 4];
            *(uint4*)b1.u = *(const uint4*)&B[(4 + quad) * 128 + (nt * 16 + n16) * 4];
            acc[nt] = __builtin_amdgcn_mfma_f32_16x16x32_f16(a0.h, b0.h, acc[nt], 0, 0, 0);
            acc[nt] = __builtin_amdgcn_mfma_f32_16x16x32_f16(a1.h, b1.h, acc[nt], 0, 0, 0);
        }
        __syncthreads();
    }
    uint32_t* hb = h2 + (size_t)b * RCP * HWP + px0;
#pragma unroll
    for (int nt = 0; nt < 2; ++nt)
#pragma unroll
        for (int pr = 0; pr < 2; ++pr) {
            const int m0 = wave * 16 + quad * 4 + 2 * pr;
            hb[(size_t)(wave * 8 + quad * 2 + pr) * HWP + nt * 16 + n16] =
                pkrtz(acc[nt][2 * pr] + rb[m0], acc[nt][2 * pr + 1] + rb[m0 + 1]);
        }
}

// ---- fused MFMA kern-gen + pk-f16 involution --------------------------------
// LDS: sXh 16.25 KB + (ldsB 14 KB overlaid with sK 10.7 KB) = 30.3 KB -> 4-5 blocks/CU
__global__ __launch_bounds__(256, 4)
void invol_fused(const float* __restrict__ x, const uint32_t* __restrict__ h2,
                 const uint32_t* __restrict__ sw2, const float* __restrict__ sb,
                 float* __restrict__ out)
{
    const int h0 = blockIdx.x * TH, g = blockIdx.y, b = blockIdx.z;

    __shared__ __align__(16) uint32_t sXh[16 * XPL];      // f16 x, [ch][row][64f16]
    __shared__ __align__(16) uint32_t U[8 * 448];         // ldsB [q4*448+px*4+jj]; later sK f16 [tap*112+px]

    const int t = threadIdx.x;
    const int wave = t >> 6, lane = t & 63, quad = lane >> 4, n16 = lane & 15;

    // A-frags from global sw2 (wave-uniform row block, L2-hot)
    const int mt0 = wave * 16 + n16;
    const int mtap = mt0 > 48 ? 48 : mt0;
    const uint32_t* swr = sw2 + ((size_t)g * KK + mtap) * RCP + quad * 4;
    frag a0, a1;
    *(uint4*)a0.u = *(const uint4*)swr;
    *(uint4*)a1.u = *(const uint4*)(swr + 16);

    float bvv[4];
#pragma unroll
    for (int reg = 0; reg < 4; ++reg) {
        const int tp = wave * 16 + quad * 4 + reg;
        bvv[reg] = (tp < KK) ? sb[g * KK + tp] : 0.f;
    }

    // stage h2 -> ldsB in B-frag order (one b128 write per 4-channel gather)
    {
        const uint32_t* hb = h2 + (size_t)b * RCP * HWP + h0 * WW;
#pragma unroll
        for (int k = 0; k < 4; ++k) {
            const int i = t + 256 * k;                  // 896 slots
            if (i < 896) {
                const int px = i % 112, q4 = i / 112;
                uint4 w;
                w.x = hb[(size_t)(q4 * 4 + 0) * HWP + px];
                w.y = hb[(size_t)(q4 * 4 + 1) * HWP + px];
                w.z = hb[(size_t)(q4 * 4 + 2) * HWP + px];
                w.w = hb[(size_t)(q4 * 4 + 3) * HWP + px];
                *(uint4*)&U[q4 * 448 + px * 4] = w;
            }
        }
    }

    // halo zero: f16 cols 0..3 / 60..63 per (ch,row) — one b64 per thread
    {
        const int ch = t >> 4, rr = (t >> 1) & 7, side = t & 1;
        uint2 z; z.x = 0; z.y = 0;
        *(uint2*)&sXh[ch * XPL + rr * XROW + (side ? 30 : 0)] = z;
    }

    // x interior -> f16 (invalid rows write zero)
    {
        const float* xb = x + (size_t)(b * CC + g * CGR) * HWP;
#pragma unroll
        for (int k = 0; k < 7; ++k) {
            const int i = t + 256 * k;                  // 1792 exact
            const int w4 = i % 14, rr = (i / 14) % 8, ch = i / 112;
            const int hh = h0 - 3 + rr;
            float4 v = make_float4(0.f, 0.f, 0.f, 0.f);
            if (hh >= 0 && hh < HH)
                v = *(const float4*)&xb[(size_t)ch * HWP + hh * WW + 4 * w4];
            uint2 p; p.x = pkrtz(v.x, v.y); p.y = pkrtz(v.z, v.w);
            *(uint2*)&sXh[ch * XPL + rr * XROW + 2 + 2 * w4] = p;
        }
    }
    __syncthreads();                                    // barrier 1

    // MFMA: K[49][112] = SW[49][64] @ H[64][112]; B-frag = one b128
    v4f acc[7];
#pragma unroll
    for (int nt = 0; nt < 7; ++nt) acc[nt] = v4f{0.f,0.f,0.f,0.f};
#pragma unroll
    for (int nt = 0; nt < 7; ++nt) {
        const int pxm = (nt * 16 + n16) * 4;
        frag b0, b1;
        *(uint4*)b0.u = *(const uint4*)&U[quad * 448 + pxm];
        *(uint4*)b1.u = *(const uint4*)&U[(4 + quad) * 448 + pxm];
        acc[nt] = __builtin_amdgcn_mfma_f32_16x16x32_f16(a0.h, b0.h, acc[nt], 0, 0, 0);
        acc[nt] = __builtin_amdgcn_mfma_f32_16x16x32_f16(a1.h, b1.h, acc[nt], 0, 0, 0);
    }
    __syncthreads();                                    // barrier 2: ldsB dead

    // epilogue -> sK f16 [tap][112]
    {
        _Float16* sK = (_Float16*)U;
#pragma unroll
        for (int nt = 0; nt < 7; ++nt) {
            const int px = nt * 16 + n16;
#pragma unroll
            for (int reg = 0; reg < 4; ++reg) {
                const int tp = wave * 16 + quad * 4 + reg;
                if (tp < KK) sK[tp * 112 + px] = (_Float16)(acc[nt][reg] + bvv[reg]);
            }
        }
    }
    __syncthreads();                                    // barrier 3

    // phase C: thread=(ch,r,wq), 8 outputs along w via v_pk_fma_f16
    if (t < 224) {
        const int ch = t & 15, q = t >> 4, r = q & 1, wq = q >> 1;
        const uint32_t* xpl = &sXh[ch * XPL + 4 * wq];
        float o0=0,o1=0,o2=0,o3=0,o4=0,o5=0,o6=0,o7=0;
#pragma unroll
        for (int kh = 0; kh < KT; ++kh) {
            const int rr = r + kh;
            uint32_t E[8];
            *(uint4*)&E[0] = *(const uint4*)&xpl[rr * XROW];
            *(uint4*)&E[4] = *(const uint4*)&xpl[rr * XROW + 4];
            uint32_t O[7];
#pragma unroll
            for (int j = 0; j < 7; ++j) O[j] = __builtin_amdgcn_alignbit(E[j + 1], E[j], 16);
            pk32 va0, va1, va2, va3;
            va0.u = va1.u = va2.u = va3.u = 0;
            const uint32_t* kq = &U[(kh * KT) * 56 + r * 28 + 4 * wq];
#pragma unroll
            for (int kw = 0; kw < KT; ++kw) {
                const uint4 kk = *(const uint4*)&kq[kw * 56];
                pk32 k0, k1, k2, k3; k0.u = kk.x; k1.u = kk.y; k2.u = kk.z; k3.u = kk.w;
                pk32 s0, s1, s2, s3;
                if (kw & 1) {
                    const int e = (kw + 1) >> 1;
                    s0.u = E[e]; s1.u = E[e + 1]; s2.u = E[e + 2]; s3.u = E[e + 3];
                } else {
                    const int oI = kw >> 1;
                    s0.u = O[oI]; s1.u = O[oI + 1]; s2.u = O[oI + 2]; s3.u = O[oI + 3];
                }
                va0.hh = __hfma2(k0.hh, s0.hh, va0.hh);
                va1.hh = __hfma2(k1.hh, s1.hh, va1.hh);
                va2.hh = __hfma2(k2.hh, s2.hh, va2.hh);
                va3.hh = __hfma2(k3.hh, s3.hh, va3.hh);
            }
            const float2 f0 = __half22float2(va0.hh); o0 += f0.x; o1 += f0.y;
            const float2 f1 = __half22float2(va1.hh); o2 += f1.x; o3 += f1.y;
            const float2 f2 = __half22float2(va2.hh); o4 += f2.x; o5 += f2.y;
            const float2 f3 = __half22float2(va3.hh); o6 += f3.x; o7 += f3.y;
        }
        float* op = out + (size_t)(b * CC + g * CGR + ch) * HWP + (h0 + r) * WW + 8 * wq;
        *(float4*)&op[0] = make_float4(o0, o1, o2, o3);
        *(float4*)&op[4] = make_float4(o4, o5, o6, o7);
    }
}

extern "C" void kernel_launch(void* const* d_in, const int* in_sizes, int n_in,
                              void* d_out, int out_size, void* d_ws, size_t ws_size,
                              hipStream_t stream)
{
    const float* x  = (const float*)d_in[0];   // (4,256,56,56)
    const float* rw = (const float*)d_in[1];   // (64,256)
    const float* rb = (const float*)d_in[2];   // (64,)
    const float* sw = (const float*)d_in[3];   // (784,64)
    const float* sb = (const float*)d_in[4];   // (784,)
    float* out  = (float*)d_out;               // (4,256,56,56)

    uint32_t* h2  = (uint32_t*)d_ws;           // (4,32,3136) u32
    uint32_t* sw2 = h2 + 4 * RCP * HWP;        // 25088 u32
    uint32_t* rw2 = sw2 + 25088;               // 8192 u32

    pack_weights<<<dim3(130, 1, 1), 256, 0, stream>>>(sw, rw, sw2, rw2);
    gemm1_mfma<<<dim3(HWP / 32, 1, 4), 256, 0, stream>>>(rw2, rb, x, h2);
    invol_fused<<<dim3(HH / TH, GG, 4), 256, 0, stream>>>(x, h2, sw2, sb, out);
}